// Round 1
// baseline (349.705 us; speedup 1.0000x reference)
//
#include <hip/hip_runtime.h>
#include <hip/hip_bf16.h>

typedef float f32x4 __attribute__((ext_vector_type(4)));
typedef __bf16 bf16x8 __attribute__((ext_vector_type(8)));
typedef unsigned int u32;
typedef unsigned short u16;

#define SEQ   4096
#define DM    1024
#define HEADS 16
#define DH    64

// ---------------- helpers ----------------
__device__ __forceinline__ void async16(void* lds, const void* g) {
  __builtin_amdgcn_global_load_lds((const __attribute__((address_space(1))) u32*)g,
                                   (__attribute__((address_space(3))) u32*)lds, 16, 0, 0);
}

// XOR swizzle for 128B-row LDS tiles: spreads column-slice reads across banks.
// row -> byte base row*128; off = byte offset within row.
__device__ __forceinline__ int swz(int row, int off) {
  return row * 128 + (off ^ ((((row >> 3) ^ row) & 7) << 4));
}

__device__ __forceinline__ float ubf2f(u32 u) {
  union { u32 x; float f; } c; c.x = u << 16; return c.f;
}
__device__ __forceinline__ u32 packbf(float a, float b) {
  __hip_bfloat16 ha = __float2bfloat16(a), hb = __float2bfloat16(b);
  return (u32)(*(u16*)&ha) | ((u32)(*(u16*)&hb) << 16);
}

// ---------------- prep: fp32 -> bf16 ----------------
__global__ __launch_bounds__(256) void prep_kernel(
    const float* __restrict__ x,  const float* __restrict__ Wq,
    const float* __restrict__ Wk, const float* __restrict__ Wv,
    const float* __restrict__ Wo, const float* __restrict__ bq,
    const float* __restrict__ bk, const float* __restrict__ bv,
    __hip_bfloat16* __restrict__ xb, __hip_bfloat16* __restrict__ Wqkv,
    __hip_bfloat16* __restrict__ Wob, float* __restrict__ bqkv)
{
  const int NX = SEQ * DM;
  const int NW = DM * DM;
  const int TOT = NX + 4 * NW + 3 * DM;
  for (int idx = blockIdx.x * 256 + threadIdx.x; idx < TOT; idx += gridDim.x * 256) {
    if (idx < NX) {
      xb[idx] = __float2bfloat16(x[idx]);
    } else if (idx < NX + 3 * NW) {
      int j = idx - NX; int m = j >> 20; int r = j & (NW - 1);
      const float* W = (m == 0) ? Wq : ((m == 1) ? Wk : Wv);
      Wqkv[j] = __float2bfloat16(W[r]);
    } else if (idx < NX + 4 * NW) {
      int r = idx - NX - 3 * NW;
      Wob[r] = __float2bfloat16(Wo[r]);
    } else {
      int r = idx - NX - 4 * NW;
      const float* b = (r < DM) ? bq : ((r < 2 * DM) ? bk : bv);
      bqkv[r] = b[r & (DM - 1)];
    }
  }
}

// ---------------- GEMM: C[M][N(out split per 1024)] = A[M][K] * B[N][K]^T + bias ----------------
// 128x128 tile, BK=32, 4 waves (2x2), global_load_lds staging, 2-phase prefetch.
template<bool F32OUT>
__global__ __launch_bounds__(256) void gemm_bt(
    const __hip_bfloat16* __restrict__ A,
    const __hip_bfloat16* __restrict__ B,
    const float* __restrict__ bias,
    void* __restrict__ C,
    int M, int N, int K)
{
  __shared__ __hip_bfloat16 As[2][128 * 32];
  __shared__ __hip_bfloat16 Bs[2][128 * 32];
  const int tid = threadIdx.x;
  const int wid = tid >> 6, lane = tid & 63;
  const int l15 = lane & 15, l4 = lane >> 4;
  const int wr = wid >> 1, wc = wid & 1;
  const int bm = blockIdx.y * 128, bn = blockIdx.x * 128;

  f32x4 acc[4][4] = {};

  auto stage = [&](int buf, int k0) {
#pragma unroll
    for (int c = 0; c < 2; ++c) {
      int li = c * 256 + tid;
      const __hip_bfloat16* ga = A + (size_t)(bm + (li >> 2)) * K + k0 + (li & 3) * 8;
      async16((char*)(&As[buf][0]) + (c * 256 + wid * 64) * 16, ga);
    }
#pragma unroll
    for (int c = 0; c < 2; ++c) {
      int li = c * 256 + tid;
      const __hip_bfloat16* gb = B + (size_t)(bn + (li >> 2)) * K + k0 + (li & 3) * 8;
      async16((char*)(&Bs[buf][0]) + (c * 256 + wid * 64) * 16, gb);
    }
  };

  stage(0, 0);
  __syncthreads();
  const int nk = K >> 5;
  int cur = 0;
  for (int t = 0; t < nk; ++t) {
    if (t + 1 < nk) stage(cur ^ 1, (t + 1) << 5);
    bf16x8 af[4], bfr[4];
#pragma unroll
    for (int m = 0; m < 4; ++m)
      af[m] = *(const bf16x8*)(&As[cur][(wr * 64 + m * 16 + l15) * 32 + l4 * 8]);
#pragma unroll
    for (int n = 0; n < 4; ++n)
      bfr[n] = *(const bf16x8*)(&Bs[cur][(wc * 64 + n * 16 + l15) * 32 + l4 * 8]);
#pragma unroll
    for (int m = 0; m < 4; ++m)
#pragma unroll
      for (int n = 0; n < 4; ++n)
        acc[m][n] = __builtin_amdgcn_mfma_f32_16x16x32_bf16(af[m], bfr[n], acc[m][n], 0, 0, 0);
    __syncthreads();
    cur ^= 1;
  }

  // epilogue: output index splits every 1024 columns into its own [4096][1024] matrix
#pragma unroll
  for (int m = 0; m < 4; ++m) {
#pragma unroll
    for (int n = 0; n < 4; ++n) {
#pragma unroll
      for (int i = 0; i < 4; ++i) {
        int row = bm + wr * 64 + m * 16 + l4 * 4 + i;
        int col = bn + wc * 64 + n * 16 + l15;
        float v = acc[m][n][i] + bias[col];
        int mat = col >> 10;
        int cm = col & 1023;
        size_t oidx = ((size_t)mat << 22) + (size_t)row * DM + cm;
        if constexpr (F32OUT) ((float*)C)[oidx] = v;
        else ((__hip_bfloat16*)C)[oidx] = __float2bfloat16(v);
      }
    }
  }
}

// ---------------- RoPE (in-place, flat-head-view positions), Q scaled by 0.125 ----------------
__global__ __launch_bounds__(256) void rope_kernel(__hip_bfloat16* __restrict__ Q,
                                                   __hip_bfloat16* __restrict__ K)
{
  const int tid = blockIdx.x * 256 + threadIdx.x;   // 0 .. 2^21-1 (pair index)
  const int i  = tid & 31;                          // pair within head-dim
  const int s2 = (tid >> 5) & (SEQ - 1);            // reinterpreted sequence position
  float inv = exp2f(-0.41524101186092f * (float)i); // 10000^(-2i/64)
  float ang = (float)s2 * inv;
  float sn, cs;
  sincosf(ang, &sn, &cs);
  size_t off = (size_t)tid * 2;
  u32 qw = *(u32*)(Q + off);
  float q1 = ubf2f(qw & 0xffffu), q2 = ubf2f(qw >> 16);
  *(u32*)(Q + off) = packbf((q1 * cs - q2 * sn) * 0.125f, (q1 * sn + q2 * cs) * 0.125f);
  u32 kw = *(u32*)(K + off);
  float k1 = ubf2f(kw & 0xffffu), k2 = ubf2f(kw >> 16);
  *(u32*)(K + off) = packbf(k1 * cs - k2 * sn, k1 * sn + k2 * cs);
}

// ---------------- causal flash attention ----------------
// grid (64 q-tiles, 16 heads), 256 threads = 4 waves x 16 q-rows. KV tiles of 64.
__global__ __launch_bounds__(256) void attn_kernel(
    const __hip_bfloat16* __restrict__ Q,   // [16][4096][64] flat, pre-scaled
    const __hip_bfloat16* __restrict__ K,
    const __hip_bfloat16* __restrict__ V,
    __hip_bfloat16* __restrict__ O)         // [16][4096][64] flat
{
  const int qb = blockIdx.x, h = blockIdx.y;
  const int tid = threadIdx.x, wid = tid >> 6, lane = tid & 63;
  const int l15 = lane & 15, l4 = lane >> 4;
  __shared__ __hip_bfloat16 Ks[64 * 64];      // [kv][d], swizzled rows
  __shared__ __hip_bfloat16 Vs[64 * 64];      // transposed [d][kv], swizzled rows
  __shared__ __hip_bfloat16 Ps[4][16 * 64];   // per-wave P tile

  const size_t hbase = (size_t)h * SEQ * DH;
  const int q0w = qb * 64 + wid * 16;

  bf16x8 qf[2];
#pragma unroll
  for (int kk = 0; kk < 2; ++kk)
    qf[kk] = *(const bf16x8*)(Q + hbase + (size_t)(q0w + l15) * DH + kk * 32 + l4 * 8);

  f32x4 oacc[4] = {};
  float mreg[4], lreg[4];
#pragma unroll
  for (int i = 0; i < 4; ++i) { mreg[i] = -1e30f; lreg[i] = 0.f; }

  char* pb = (char*)(&Ps[wid][0]);
  const int nt = qb + 1;
  for (int t = 0; t < nt; ++t) {
    const int kb = t * 64;
    __syncthreads();   // previous tile's LDS reads done
    // stage K tile
#pragma unroll
    for (int c = 0; c < 2; ++c) {
      int li = c * 256 + tid;
      int row = li >> 3, colc = li & 7;
      int4 d = *(const int4*)(K + hbase + (size_t)(kb + row) * DH + colc * 8);
      *(int4*)((char*)Ks + swz(row, colc * 16)) = d;
    }
    // stage V transposed: thread loads 2 kv rows x 8 d, writes packed kv-pairs
    {
      int rp = tid >> 3, colc = tid & 7;     // kv pair base = 2*rp
      const __hip_bfloat16* vp = V + hbase + (size_t)(kb + 2 * rp) * DH + colc * 8;
      int4 v0 = *(const int4*)vp;
      int4 v1 = *(const int4*)(vp + DH);
      const u16* a0 = (const u16*)&v0; const u16* a1 = (const u16*)&v1;
#pragma unroll
      for (int j = 0; j < 8; ++j) {
        u32 w = (u32)a0[j] | ((u32)a1[j] << 16);
        *(u32*)((char*)Vs + swz(colc * 8 + j, rp * 4)) = w;
      }
    }
    __syncthreads();
    // S = Q K^T  (16 x 64 per wave)
    f32x4 s[4];
#pragma unroll
    for (int g = 0; g < 4; ++g) {
      f32x4 z = {0.f, 0.f, 0.f, 0.f};
#pragma unroll
      for (int kk = 0; kk < 2; ++kk) {
        bf16x8 kf = *(const bf16x8*)((char*)Ks + swz(g * 16 + l15, kk * 64 + l4 * 16));
        z = __builtin_amdgcn_mfma_f32_16x16x32_bf16(qf[kk], kf, z, 0, 0, 0);
      }
      s[g] = z;
    }
    // causal mask (only the diagonal tile needs it)
    if (t == nt - 1) {
#pragma unroll
      for (int g = 0; g < 4; ++g)
#pragma unroll
        for (int i = 0; i < 4; ++i) {
          int qrow = q0w + l4 * 4 + i;
          int kv = kb + g * 16 + l15;
          if (kv > qrow) s[g][i] = -1e30f;
        }
    }
    // online softmax (rows spread over 16-lane groups)
    float scale[4];
#pragma unroll
    for (int i = 0; i < 4; ++i) {
      float mx = fmaxf(fmaxf(s[0][i], s[1][i]), fmaxf(s[2][i], s[3][i]));
      mx = fmaxf(mx, __shfl_xor(mx, 1));
      mx = fmaxf(mx, __shfl_xor(mx, 2));
      mx = fmaxf(mx, __shfl_xor(mx, 4));
      mx = fmaxf(mx, __shfl_xor(mx, 8));
      float mnew = fmaxf(mreg[i], mx);
      scale[i] = __expf(mreg[i] - mnew);
      mreg[i] = mnew;
    }
#pragma unroll
    for (int g = 0; g < 4; ++g)
#pragma unroll
      for (int i = 0; i < 4; ++i)
        s[g][i] = __expf(s[g][i] - mreg[i]);
#pragma unroll
    for (int i = 0; i < 4; ++i) {
      float rs = s[0][i] + s[1][i] + s[2][i] + s[3][i];
      rs += __shfl_xor(rs, 1);
      rs += __shfl_xor(rs, 2);
      rs += __shfl_xor(rs, 4);
      rs += __shfl_xor(rs, 8);
      lreg[i] = lreg[i] * scale[i] + rs;
#pragma unroll
      for (int n = 0; n < 4; ++n) oacc[n][i] *= scale[i];
    }
    // P -> per-wave LDS (bf16, swizzled)
#pragma unroll
    for (int g = 0; g < 4; ++g)
#pragma unroll
      for (int i = 0; i < 4; ++i) {
        int row = l4 * 4 + i, col = g * 16 + l15;
        *(__hip_bfloat16*)(pb + swz(row, col * 2)) = __float2bfloat16(s[g][i]);
      }
    asm volatile("s_waitcnt lgkmcnt(0)" ::: "memory");
    // O += P V
#pragma unroll
    for (int kk = 0; kk < 2; ++kk) {
      bf16x8 pa = *(const bf16x8*)(pb + swz(l15, kk * 64 + l4 * 16));
#pragma unroll
      for (int n = 0; n < 4; ++n) {
        bf16x8 vb = *(const bf16x8*)((char*)Vs + swz(n * 16 + l15, kk * 64 + l4 * 16));
        oacc[n] = __builtin_amdgcn_mfma_f32_16x16x32_bf16(pa, vb, oacc[n], 0, 0, 0);
      }
    }
  }
  // epilogue: write flat [h][s2][d]
#pragma unroll
  for (int i = 0; i < 4; ++i) {
    float rinv = 1.0f / lreg[i];
#pragma unroll
    for (int n = 0; n < 4; ++n) {
      int row = q0w + l4 * 4 + i;
      int col = n * 16 + l15;
      O[hbase + (size_t)row * DH + col] = __float2bfloat16(oacc[n][i] * rinv);
    }
  }
}

// ---------------- launch ----------------
extern "C" void kernel_launch(void* const* d_in, const int* in_sizes, int n_in,
                              void* d_out, int out_size, void* d_ws, size_t ws_size,
                              hipStream_t stream) {
  (void)in_sizes; (void)n_in; (void)out_size; (void)ws_size;
  const float* x  = (const float*)d_in[0];
  const float* Wq = (const float*)d_in[1];
  const float* bq = (const float*)d_in[2];
  const float* Wk = (const float*)d_in[3];
  const float* bk = (const float*)d_in[4];
  const float* Wv = (const float*)d_in[5];
  const float* bv = (const float*)d_in[6];
  const float* Wo = (const float*)d_in[7];
  const float* bo = (const float*)d_in[8];

  char* ws = (char*)d_ws;
  __hip_bfloat16* xb     = (__hip_bfloat16*)(ws + 0);          // 8 MB
  __hip_bfloat16* Wqkv   = (__hip_bfloat16*)(ws + 8388608);    // 6 MB [3072][1024]
  __hip_bfloat16* Wob    = (__hip_bfloat16*)(ws + 14680064);   // 2 MB
  float*          bqkv   = (float*)(ws + 16777216);            // 12 KB
  __hip_bfloat16* Qbuf   = (__hip_bfloat16*)(ws + 16789504);   // 8 MB (also [16][4096][64])
  __hip_bfloat16* Kbuf   = (__hip_bfloat16*)(ws + 25178112);   // 8 MB (contiguous after Qbuf)
  __hip_bfloat16* Vbuf   = (__hip_bfloat16*)(ws + 33566720);   // 8 MB (contiguous after Kbuf)
  __hip_bfloat16* concat = (__hip_bfloat16*)(ws + 41955328);   // 8 MB

  prep_kernel<<<2048, 256, 0, stream>>>(x, Wq, Wk, Wv, Wo, bq, bk, bv, xb, Wqkv, Wob, bqkv);
  // QKV projection: output matrices land contiguously in Qbuf/Kbuf/Vbuf via col>>10 split
  gemm_bt<false><<<dim3(24, 32), 256, 0, stream>>>(xb, Wqkv, bqkv, (void*)Qbuf, SEQ, 3072, DM);
  rope_kernel<<<8192, 256, 0, stream>>>(Qbuf, Kbuf);
  attn_kernel<<<dim3(64, HEADS), 256, 0, stream>>>(Qbuf, Kbuf, Vbuf, concat);
  gemm_bt<true><<<dim3(8, 32), 256, 0, stream>>>(concat, Wob, bo, d_out, SEQ, DM, DM);
}

// Round 2
// 242.603 us; speedup vs baseline: 1.4415x; 1.4415x over previous
//
#include <hip/hip_runtime.h>
#include <hip/hip_bf16.h>

typedef float f32x4 __attribute__((ext_vector_type(4)));
typedef __bf16 bf16x8 __attribute__((ext_vector_type(8)));
typedef unsigned int u32;
typedef unsigned short u16;

#define SEQ   4096
#define DM    1024
#define HEADS 16
#define DH    64

// ---------------- helpers ----------------
__device__ __forceinline__ void async16(void* lds, const void* g) {
  __builtin_amdgcn_global_load_lds((const __attribute__((address_space(1))) u32*)g,
                                   (__attribute__((address_space(3))) u32*)lds, 16, 0, 0);
}

// XOR swizzle for 128B-row LDS tiles: spreads column-slice reads across banks.
__device__ __forceinline__ int swz(int row, int off) {
  return row * 128 + (off ^ ((((row >> 3) ^ row) & 7) << 4));
}

__device__ __forceinline__ float ubf2f(u32 u) {
  union { u32 x; float f; } c; c.x = u << 16; return c.f;
}
__device__ __forceinline__ u32 packbf(float a, float b) {
  __hip_bfloat16 ha = __float2bfloat16(a), hb = __float2bfloat16(b);
  return (u32)(*(u16*)&ha) | ((u32)(*(u16*)&hb) << 16);
}

// ---------------- prep: fp32 -> bf16 ----------------
__global__ __launch_bounds__(256) void prep_kernel(
    const float* __restrict__ x,  const float* __restrict__ Wq,
    const float* __restrict__ Wk, const float* __restrict__ Wv,
    const float* __restrict__ Wo, const float* __restrict__ bq,
    const float* __restrict__ bk, const float* __restrict__ bv,
    __hip_bfloat16* __restrict__ xb, __hip_bfloat16* __restrict__ Wqkv,
    __hip_bfloat16* __restrict__ Wob, float* __restrict__ bqkv)
{
  const int NX = SEQ * DM;
  const int NW = DM * DM;
  const int TOT = NX + 4 * NW + 3 * DM;
  for (int idx = blockIdx.x * 256 + threadIdx.x; idx < TOT; idx += gridDim.x * 256) {
    if (idx < NX) {
      xb[idx] = __float2bfloat16(x[idx]);
    } else if (idx < NX + 3 * NW) {
      int j = idx - NX; int m = j >> 20; int r = j & (NW - 1);
      const float* W = (m == 0) ? Wq : ((m == 1) ? Wk : Wv);
      Wqkv[j] = __float2bfloat16(W[r]);
    } else if (idx < NX + 4 * NW) {
      int r = idx - NX - 3 * NW;
      Wob[r] = __float2bfloat16(Wo[r]);
    } else {
      int r = idx - NX - 4 * NW;
      const float* b = (r < DM) ? bq : ((r < 2 * DM) ? bk : bv);
      bqkv[r] = b[r & (DM - 1)];
    }
  }
}

// ---------------- GEMM: C[M][N(out split per 1024)] = A[M][K] * B[N][K]^T + bias ----------------
template<bool F32OUT>
__global__ __launch_bounds__(256) void gemm_bt(
    const __hip_bfloat16* __restrict__ A,
    const __hip_bfloat16* __restrict__ B,
    const float* __restrict__ bias,
    void* __restrict__ C,
    int M, int N, int K)
{
  __shared__ __hip_bfloat16 As[2][128 * 32];
  __shared__ __hip_bfloat16 Bs[2][128 * 32];
  const int tid = threadIdx.x;
  const int wid = tid >> 6, lane = tid & 63;
  const int l15 = lane & 15, l4 = lane >> 4;
  const int wr = wid >> 1, wc = wid & 1;
  const int bm = blockIdx.y * 128, bn = blockIdx.x * 128;

  f32x4 acc[4][4] = {};

  auto stage = [&](int buf, int k0) {
#pragma unroll
    for (int c = 0; c < 2; ++c) {
      int li = c * 256 + tid;
      const __hip_bfloat16* ga = A + (size_t)(bm + (li >> 2)) * K + k0 + (li & 3) * 8;
      async16((char*)(&As[buf][0]) + (c * 256 + wid * 64) * 16, ga);
    }
#pragma unroll
    for (int c = 0; c < 2; ++c) {
      int li = c * 256 + tid;
      const __hip_bfloat16* gb = B + (size_t)(bn + (li >> 2)) * K + k0 + (li & 3) * 8;
      async16((char*)(&Bs[buf][0]) + (c * 256 + wid * 64) * 16, gb);
    }
  };

  stage(0, 0);
  __syncthreads();
  const int nk = K >> 5;
  int cur = 0;
  for (int t = 0; t < nk; ++t) {
    if (t + 1 < nk) stage(cur ^ 1, (t + 1) << 5);
    bf16x8 af[4], bfr[4];
#pragma unroll
    for (int m = 0; m < 4; ++m)
      af[m] = *(const bf16x8*)(&As[cur][(wr * 64 + m * 16 + l15) * 32 + l4 * 8]);
#pragma unroll
    for (int n = 0; n < 4; ++n)
      bfr[n] = *(const bf16x8*)(&Bs[cur][(wc * 64 + n * 16 + l15) * 32 + l4 * 8]);
#pragma unroll
    for (int m = 0; m < 4; ++m)
#pragma unroll
      for (int n = 0; n < 4; ++n)
        acc[m][n] = __builtin_amdgcn_mfma_f32_16x16x32_bf16(af[m], bfr[n], acc[m][n], 0, 0, 0);
    __syncthreads();
    cur ^= 1;
  }

#pragma unroll
  for (int m = 0; m < 4; ++m) {
#pragma unroll
    for (int n = 0; n < 4; ++n) {
#pragma unroll
      for (int i = 0; i < 4; ++i) {
        int row = bm + wr * 64 + m * 16 + l4 * 4 + i;
        int col = bn + wc * 64 + n * 16 + l15;
        float v = acc[m][n][i] + bias[col];
        int mat = col >> 10;
        int cm = col & 1023;
        size_t oidx = ((size_t)mat << 22) + (size_t)row * DM + cm;
        if constexpr (F32OUT) ((float*)C)[oidx] = v;
        else ((__hip_bfloat16*)C)[oidx] = __float2bfloat16(v);
      }
    }
  }
}

// ---------------- RoPE (in-place, flat-head-view positions), Q scaled by 0.125 ----------------
__global__ __launch_bounds__(256) void rope_kernel(__hip_bfloat16* __restrict__ Q,
                                                   __hip_bfloat16* __restrict__ K)
{
  const int tid = blockIdx.x * 256 + threadIdx.x;   // pair index
  const int i  = tid & 31;
  const int s2 = (tid >> 5) & (SEQ - 1);
  float inv = exp2f(-0.41524101186092f * (float)i); // 10000^(-2i/64)
  float ang = (float)s2 * inv;
  float sn, cs;
  sincosf(ang, &sn, &cs);
  size_t off = (size_t)tid * 2;
  u32 qw = *(u32*)(Q + off);
  float q1 = ubf2f(qw & 0xffffu), q2 = ubf2f(qw >> 16);
  *(u32*)(Q + off) = packbf((q1 * cs - q2 * sn) * 0.125f, (q1 * sn + q2 * cs) * 0.125f);
  u32 kw = *(u32*)(K + off);
  float k1 = ubf2f(kw & 0xffffu), k2 = ubf2f(kw >> 16);
  *(u32*)(K + off) = packbf(k1 * cs - k2 * sn, k1 * sn + k2 * cs);
}

// ---------------- causal flash attention, paired q-tiles ----------------
// grid (32 pairs, 16 heads). Block pid handles q-tiles {pid, 63-pid}: every
// block computes exactly 65 fragment-tiles (perfect causal balance).
// 4 waves x 16 q-rows per fragment. KV tiles of 64, double-buffered:
// K staged via global_load_lds with pre-swizzled per-lane source;
// V loads issued early, packed+transposed into LDS after compute.
__global__ __launch_bounds__(256) void attn_kernel(
    const __hip_bfloat16* __restrict__ Q,   // [16][4096][64] flat, pre-scaled
    const __hip_bfloat16* __restrict__ K,
    const __hip_bfloat16* __restrict__ V,
    __hip_bfloat16* __restrict__ O)
{
  const int pid = blockIdx.x, h = blockIdx.y;
  const int tid = threadIdx.x, wid = tid >> 6, lane = tid & 63;
  const int l15 = lane & 15, l4 = lane >> 4;
  __shared__ __hip_bfloat16 Ks[2][64 * 64];   // [kv][d], swizzled rows
  __shared__ __hip_bfloat16 Vs[2][64 * 64];   // transposed [d][kv], swizzled rows
  __shared__ __hip_bfloat16 Ps[4][16 * 64];   // per-wave P tile

  const size_t hbase = (size_t)h * SEQ * DH;
  const int qa = pid, qb = 63 - pid;
  const int ra = qa * 64 + wid * 16, rb = qb * 64 + wid * 16;

  // K staging: per-lane pre-swizzled global offsets, linear LDS dest.
  // issue (wid,c) covers kv rows [(wid*2+c)*8, +8); lane l -> row += l>>3,
  // 16B chunk (l&7) in LDS holds global chunk ((l&7) ^ f(row)).
  int goffK[2];
#pragma unroll
  for (int c = 0; c < 2; ++c) {
    int rowc = (wid * 2 + c) * 8 + (lane >> 3);
    int fc = ((wid * 2 + c) ^ (lane >> 3)) & 7;
    goffK[c] = rowc * DH + ((lane & 7) ^ fc) * 8;
  }
  const int rp = tid >> 3, colc = tid & 7;   // V loader: kv pair base 2*rp, d chunk colc

  bf16x8 qfa[2], qfb[2];
#pragma unroll
  for (int kk = 0; kk < 2; ++kk) {
    qfa[kk] = *(const bf16x8*)(Q + hbase + (size_t)(ra + l15) * DH + kk * 32 + l4 * 8);
    qfb[kk] = *(const bf16x8*)(Q + hbase + (size_t)(rb + l15) * DH + kk * 32 + l4 * 8);
  }

  f32x4 oa[4] = {}, ob[4] = {};
  float ma[4], la[4], mb[4], lb[4];
#pragma unroll
  for (int i = 0; i < 4; ++i) { ma[i] = mb[i] = -1e30f; la[i] = lb[i] = 0.f; }

  char* pb = (char*)(&Ps[wid][0]);
  const int TB = 64 - pid;

  auto stageK = [&](int buf, int tt) {
#pragma unroll
    for (int c = 0; c < 2; ++c)
      async16((char*)(&Ks[buf][0]) + (wid * 2 + c) * 1024,
              K + hbase + (size_t)tt * 64 * DH + goffK[c]);
  };
  auto loadV = [&](int tt, int4& v0, int4& v1) {
    const __hip_bfloat16* vp = V + hbase + (size_t)(tt * 64 + 2 * rp) * DH + colc * 8;
    v0 = *(const int4*)vp; v1 = *(const int4*)(vp + DH);
  };
  auto writeV = [&](int buf, const int4& v0, const int4& v1) {
    const u16* a0 = (const u16*)&v0; const u16* a1 = (const u16*)&v1;
#pragma unroll
    for (int j = 0; j < 8; ++j) {
      u32 w = (u32)a0[j] | ((u32)a1[j] << 16);
      *(u32*)((char*)(&Vs[buf][0]) + swz(colc * 8 + j, rp * 4)) = w;
    }
  };

  auto frag = [&](int buf, int kb, bool diag, const bf16x8* qf, int r0,
                  float* m, float* l, f32x4* oacc) {
    f32x4 s[4];
#pragma unroll
    for (int g = 0; g < 4; ++g) {
      f32x4 z = {0.f, 0.f, 0.f, 0.f};
#pragma unroll
      for (int kk = 0; kk < 2; ++kk) {
        bf16x8 kf = *(const bf16x8*)((char*)(&Ks[buf][0]) + swz(g * 16 + l15, kk * 64 + l4 * 16));
        z = __builtin_amdgcn_mfma_f32_16x16x32_bf16(qf[kk], kf, z, 0, 0, 0);
      }
      s[g] = z;
    }
    if (diag) {
#pragma unroll
      for (int g = 0; g < 4; ++g)
#pragma unroll
        for (int i = 0; i < 4; ++i)
          if (kb + g * 16 + l15 > r0 + l4 * 4 + i) s[g][i] = -1e30f;
    }
    float scale[4];
#pragma unroll
    for (int i = 0; i < 4; ++i) {
      float mx = fmaxf(fmaxf(s[0][i], s[1][i]), fmaxf(s[2][i], s[3][i]));
      mx = fmaxf(mx, __shfl_xor(mx, 1));
      mx = fmaxf(mx, __shfl_xor(mx, 2));
      mx = fmaxf(mx, __shfl_xor(mx, 4));
      mx = fmaxf(mx, __shfl_xor(mx, 8));
      float mn = fmaxf(m[i], mx);
      scale[i] = __expf(m[i] - mn);
      m[i] = mn;
    }
#pragma unroll
    for (int g = 0; g < 4; ++g)
#pragma unroll
      for (int i = 0; i < 4; ++i)
        s[g][i] = __expf(s[g][i] - m[i]);
#pragma unroll
    for (int i = 0; i < 4; ++i) {
      float rs = s[0][i] + s[1][i] + s[2][i] + s[3][i];
      rs += __shfl_xor(rs, 1);
      rs += __shfl_xor(rs, 2);
      rs += __shfl_xor(rs, 4);
      rs += __shfl_xor(rs, 8);
      l[i] = l[i] * scale[i] + rs;
#pragma unroll
      for (int n = 0; n < 4; ++n) oacc[n][i] *= scale[i];
    }
#pragma unroll
    for (int g = 0; g < 4; ++g)
#pragma unroll
      for (int i = 0; i < 4; ++i)
        *(__hip_bfloat16*)(pb + swz(l4 * 4 + i, (g * 16 + l15) * 2)) = __float2bfloat16(s[g][i]);
    asm volatile("s_waitcnt lgkmcnt(0)" ::: "memory");
#pragma unroll
    for (int kk = 0; kk < 2; ++kk) {
      bf16x8 pa = *(const bf16x8*)(pb + swz(l15, kk * 64 + l4 * 16));
#pragma unroll
      for (int n = 0; n < 4; ++n) {
        bf16x8 vb = *(const bf16x8*)((char*)(&Vs[buf][0]) + swz(n * 16 + l15, kk * 64 + l4 * 16));
        oacc[n] = __builtin_amdgcn_mfma_f32_16x16x32_bf16(pa, vb, oacc[n], 0, 0, 0);
      }
    }
  };

  // prologue: tile 0 into buffer 0
  stageK(0, 0);
  int4 v0, v1;
  loadV(0, v0, v1);
  writeV(0, v0, v1);
  __syncthreads();   // drains global_load_lds (vmcnt) + ds writes

  for (int t = 0; t < TB; ++t) {
    const int cur = t & 1, nxt = cur ^ 1;
    const int kb = t * 64;
    const bool pre = (t + 1 < TB);
    if (pre) { stageK(nxt, t + 1); loadV(t + 1, v0, v1); }   // prefetch issue
    frag(cur, kb, t == qb, qfb, rb, mb, lb, ob);             // high tile: always
    if (t <= qa) frag(cur, kb, t == qa, qfa, ra, ma, la, oa); // low tile
    if (pre) writeV(nxt, v0, v1);                            // write-late (T14)
    __syncthreads();
  }

  // epilogue
#pragma unroll
  for (int i = 0; i < 4; ++i) {
    float ria = 1.0f / la[i], rib = 1.0f / lb[i];
#pragma unroll
    for (int n = 0; n < 4; ++n) {
      O[hbase + (size_t)(ra + l4 * 4 + i) * DH + n * 16 + l15] = __float2bfloat16(oa[n][i] * ria);
      O[hbase + (size_t)(rb + l4 * 4 + i) * DH + n * 16 + l15] = __float2bfloat16(ob[n][i] * rib);
    }
  }
}

// ---------------- launch ----------------
extern "C" void kernel_launch(void* const* d_in, const int* in_sizes, int n_in,
                              void* d_out, int out_size, void* d_ws, size_t ws_size,
                              hipStream_t stream) {
  (void)in_sizes; (void)n_in; (void)out_size; (void)ws_size;
  const float* x  = (const float*)d_in[0];
  const float* Wq = (const float*)d_in[1];
  const float* bq = (const float*)d_in[2];
  const float* Wk = (const float*)d_in[3];
  const float* bk = (const float*)d_in[4];
  const float* Wv = (const float*)d_in[5];
  const float* bv = (const float*)d_in[6];
  const float* Wo = (const float*)d_in[7];
  const float* bo = (const float*)d_in[8];

  char* ws = (char*)d_ws;
  __hip_bfloat16* xb     = (__hip_bfloat16*)(ws + 0);          // 8 MB
  __hip_bfloat16* Wqkv   = (__hip_bfloat16*)(ws + 8388608);    // 6 MB [3072][1024]
  __hip_bfloat16* Wob    = (__hip_bfloat16*)(ws + 14680064);   // 2 MB
  float*          bqkv   = (float*)(ws + 16777216);            // 12 KB
  __hip_bfloat16* Qbuf   = (__hip_bfloat16*)(ws + 16789504);   // 8 MB
  __hip_bfloat16* Kbuf   = (__hip_bfloat16*)(ws + 25178112);   // 8 MB
  __hip_bfloat16* Vbuf   = (__hip_bfloat16*)(ws + 33566720);   // 8 MB
  __hip_bfloat16* concat = (__hip_bfloat16*)(ws + 41955328);   // 8 MB

  prep_kernel<<<2048, 256, 0, stream>>>(x, Wq, Wk, Wv, Wo, bq, bk, bv, xb, Wqkv, Wob, bqkv);
  gemm_bt<false><<<dim3(24, 32), 256, 0, stream>>>(xb, Wqkv, bqkv, (void*)Qbuf, SEQ, 3072, DM);
  rope_kernel<<<8192, 256, 0, stream>>>(Qbuf, Kbuf);
  attn_kernel<<<dim3(32, HEADS), 256, 0, stream>>>(Qbuf, Kbuf, Vbuf, concat);
  gemm_bt<true><<<dim3(8, 32), 256, 0, stream>>>(concat, Wob, bo, d_out, SEQ, DM, DM);
}